// Round 12
// baseline (131.768 us; speedup 1.0000x reference)
//
#include <hip/hip_runtime.h>

// out[n,k] = <Cmat[k], project[n]> + d[k]   (pipeline fully linear in project)
// Reassociated as TWO passes so the big proj read is copy-shaped:
//   Pass1 k_roi: T[n][ji*512+c] = sum_hw R[ji,hw]*proj[n,c,hw]  (bilinear, 4 FMA/out)
//                205 MB contiguous-burst read -> 51 MB write.
//   Pass2 k_fin: out[n,k] = sum_d Bmat[k*25088+d]*T[n][d]  (d = ji*512+c)
//                Bmat = WH*(w3*w2*w1) IS the pass-2 weight matrix directly.
// Prep depth 2: {Y=w2*w1 || T1=WH*w3} one batched launch, then Bmat=T1*Y.
//
// ws layout (floats):
//   WH    [490][512]     off 0
//   Y     [512][512]     off 250880
//   T1    [490][512]     off 513024
//   Bmat  [490][512]     off 763904
//   T     [512][25088]   off 1014784   (51.4 MB)
//   u2    [512]          off 13859840
//   vv    [512]          off 13860352
//   dpart [10][8]        off 13860864
//   part  [128*32][40]   off 13860944

#define CHW 100352   // 512*196
#define CHW4 25088   // float4 per proj row
#define TD 25088     // reduced dim (49*512)
#define TD4 6272     // float4 per T row
#define STEP 1.8571428571428572f  // 13/7

// C[M x 512] = A[M x 512] * B[512 x 512]; 32x32 tile per block, thread = 2x2.
__global__ __launch_bounds__(256) void k_mm32(const float* __restrict__ A,
                                              const float* __restrict__ B,
                                              float* __restrict__ C, int M) {
    __shared__ float As[32][36];
    __shared__ float Bs[32][36];
    int bx = blockIdx.x, by = blockIdx.y;
    int tid = threadIdx.x;
    int lr = tid >> 3;
    int lc = (tid & 7) << 2;
    int tx = tid & 15, ty = tid >> 4;
    float a00 = 0.f, a01 = 0.f, a10 = 0.f, a11 = 0.f;
    for (int kc = 0; kc < 512; kc += 32) {
        int gr = by * 32 + lr;
        float4 av = make_float4(0.f, 0.f, 0.f, 0.f);
        if (gr < M) av = *(const float4*)&A[(size_t)gr * 512 + kc + lc];
        *(float4*)&As[lr][lc] = av;
        float4 bv = *(const float4*)&B[(size_t)(kc + lr) * 512 + bx * 32 + lc];
        *(float4*)&Bs[lr][lc] = bv;
        __syncthreads();
        #pragma unroll
        for (int kk = 0; kk < 32; ++kk) {
            float b0 = Bs[kk][tx * 2], b1 = Bs[kk][tx * 2 + 1];
            float x0 = As[ty * 2][kk], x1 = As[ty * 2 + 1][kk];
            a00 += x0 * b0; a01 += x0 * b1;
            a10 += x1 * b0; a11 += x1 * b1;
        }
        __syncthreads();
    }
    int r0 = by * 32 + ty * 2, c0 = bx * 32 + tx * 2;
    if (r0 < M)     { C[(size_t)r0 * 512 + c0] = a00; C[(size_t)r0 * 512 + c0 + 1] = a01; }
    if (r0 + 1 < M) { C[(size_t)(r0 + 1) * 512 + c0] = a10; C[(size_t)(r0 + 1) * 512 + c0 + 1] = a11; }
}

// Batched level-1: z=0 -> Y = w2*w1 (M=512); z=1 -> T1 = WH*w3 (M=490).
__global__ __launch_bounds__(256) void k_mmb(const float* __restrict__ w1,
                                             const float* __restrict__ w2,
                                             const float* __restrict__ w3,
                                             const float* __restrict__ WH,
                                             float* __restrict__ Y,
                                             float* __restrict__ T1) {
    __shared__ float As[32][36];
    __shared__ float Bs[32][36];
    const float* A; const float* B; float* C; int M;
    if (blockIdx.z == 0) { A = w2; B = w1; C = Y;  M = 512; }
    else                 { A = WH; B = w3; C = T1; M = 490; }
    int bx = blockIdx.x, by = blockIdx.y;
    int tid = threadIdx.x;
    int lr = tid >> 3;
    int lc = (tid & 7) << 2;
    int tx = tid & 15, ty = tid >> 4;
    float a00 = 0.f, a01 = 0.f, a10 = 0.f, a11 = 0.f;
    for (int kc = 0; kc < 512; kc += 32) {
        int gr = by * 32 + lr;
        float4 av = make_float4(0.f, 0.f, 0.f, 0.f);
        if (gr < M) av = *(const float4*)&A[(size_t)gr * 512 + kc + lc];
        *(float4*)&As[lr][lc] = av;
        float4 bv = *(const float4*)&B[(size_t)(kc + lr) * 512 + bx * 32 + lc];
        *(float4*)&Bs[lr][lc] = bv;
        __syncthreads();
        #pragma unroll
        for (int kk = 0; kk < 32; ++kk) {
            float b0 = Bs[kk][tx * 2], b1 = Bs[kk][tx * 2 + 1];
            float x0 = As[ty * 2][kk], x1 = As[ty * 2 + 1][kk];
            a00 += x0 * b0; a01 += x0 * b1;
            a10 += x1 * b0; a11 += x1 * b1;
        }
        __syncthreads();
    }
    int r0 = by * 32 + ty * 2, c0 = bx * 32 + tx * 2;
    if (r0 < M)     { C[(size_t)r0 * 512 + c0] = a00; C[(size_t)r0 * 512 + c0 + 1] = a01; }
    if (r0 + 1 < M) { C[(size_t)(r0 + 1) * 512 + c0] = a10; C[(size_t)(r0 + 1) * 512 + c0 + 1] = a11; }
}

// WH[r][q] = wh[k][q*49 + ji],  r = k*49 + ji
__global__ void k_whT(const float* __restrict__ w_note, const float* __restrict__ w_reg,
                      float* __restrict__ WH) {
    int r = blockIdx.x;      // 0..489
    int q = threadIdx.x;     // 0..511
    int k = r / 49, ji = r % 49;
    const float* wh = (k < 2) ? (w_note + k * 25088) : (w_reg + (k - 2) * 25088);
    WH[(size_t)r * 512 + q] = wh[q * 49 + ji];
}

// u2 = b2 + w2*b1
__global__ void k_mv1(const float* __restrict__ w2, const float* __restrict__ b1,
                      const float* __restrict__ b2, float* __restrict__ u2) {
    int o = blockIdx.x;
    int l = threadIdx.x;  // 64
    float s = 0.f;
    for (int i = l; i < 512; i += 64) s += w2[(size_t)o * 512 + i] * b1[i];
    for (int off = 32; off; off >>= 1) s += __shfl_down(s, off);
    if (l == 0) u2[o] = b2[o] + s;
}

// vv = b3 + w3*u2
__global__ void k_mv2(const float* __restrict__ w3, const float* __restrict__ u2,
                      const float* __restrict__ b3, float* __restrict__ vv) {
    int o = blockIdx.x;
    int l = threadIdx.x;  // 64
    float s = 0.f;
    for (int i = l; i < 512; i += 64) s += w3[(size_t)o * 512 + i] * u2[i];
    for (int off = 32; off; off >>= 1) s += __shfl_down(s, off);
    if (l == 0) vv[o] = b3[o] + s;
}

// dpart[k][b] = partial of sum_i wh[k][i] * vv[i/49]
__global__ void k_dvec(const float* __restrict__ w_note, const float* __restrict__ w_reg,
                       const float* __restrict__ vv, float* __restrict__ dpart) {
    int k = blockIdx.x;   // 10
    int b = blockIdx.y;   // 8
    int t = threadIdx.x;  // 256
    const float* wh = (k < 2) ? (w_note + k * 25088) : (w_reg + (k - 2) * 25088);
    float s = 0.f;
    for (int i = b * 256 + t; i < 25088; i += 2048) s += wh[i] * vv[i / 49];
    __shared__ float red[256];
    red[t] = s;
    __syncthreads();
    for (int off = 128; off; off >>= 1) {
        if (t < off) red[t] += red[t + off];
        __syncthreads();
    }
    if (t == 0) dpart[k * 8 + b] = red[0];
}

// Pass 1: block (n, chunk of 32 c). Contiguous 25 KB burst -> LDS -> 1568
// bilinear outputs -> coalesced write. Copy-shaped on purpose.
__global__ __launch_bounds__(256) void k_roi(const float* __restrict__ proj,
                                             float* __restrict__ T) {
    __shared__ float X[32][197];   // 25,216 B; stride 197 -> conflict-free col reads
    int b = blockIdx.x;            // 0..8191
    int n = b >> 4;
    int ch = b & 15;               // c0 = ch*32
    int tid = threadIdx.x;

    const float4* src = (const float4*)proj + (size_t)n * CHW4 + ch * 1568;
    for (int i = tid; i < 1568; i += 256) {
        float4 v = src[i];
        int cc = i / 49, q = i - cc * 49;
        float* xr = &X[cc][q * 4];
        xr[0] = v.x; xr[1] = v.y; xr[2] = v.z; xr[3] = v.w;
    }
    __syncthreads();

    const float base = STEP * 0.5f - 0.5f;
    for (int o = tid; o < 1568; o += 256) {
        int ji = o >> 5, cl = o & 31;
        int j = (ji * 37) >> 8;          // floor(ji/7) for ji<49
        int i2 = ji - j * 7;
        float yv = base + j * STEP;
        float xv = base + i2 * STEP;
        float y0f = floorf(yv), x0f = floorf(xv);
        float wy = yv - y0f, wx = xv - x0f;
        int y0 = (int)y0f, x0 = (int)x0f;
        const float* xr = X[cl];
        int i00 = y0 * 14 + x0;
        float v00 = xr[i00],      v01 = xr[i00 + 1];
        float v10 = xr[i00 + 14], v11 = xr[i00 + 15];
        float top = v00 + (v01 - v00) * wx;
        float bot = v10 + (v11 - v10) * wx;
        T[(size_t)n * TD + ji * 512 + ch * 32 + cl] = top + (bot - top) * wy;
    }
}

// Pass 2: block b: g = b>>3 (4 rows), xb = b&7 (slice of 784 f4).
// 3 windows of 256 + 16-wide tail; Bmat slice L2-resident; butterfly reduce.
__global__ __launch_bounds__(256) void k_fin(const float* __restrict__ T,
                                             const float* __restrict__ Bmat,
                                             float* __restrict__ part) {
    int b = blockIdx.x;          // 0..1023
    int g = b >> 3;              // 0..127
    int xb = b & 7;
    int tid = threadIdx.x;
    int wv = tid >> 6, lane = tid & 63;

    const float4* tg = (const float4*)T;
    const float4* bg = (const float4*)Bmat;
    int base = xb * 784;
    const float4* p0 = tg + (size_t)(g * 4 + 0) * TD4 + base + tid;
    const float4* p1 = p0 + TD4;
    const float4* p2 = p1 + TD4;
    const float4* p3 = p2 + TD4;
    const float4* cb = bg + base + tid;

    float acc[4][10];
    #pragma unroll
    for (int j = 0; j < 4; ++j)
        #pragma unroll
        for (int k = 0; k < 10; ++k) acc[j][k] = 0.f;

    float4 pa = p0[0], pb = p1[0], pc = p2[0], pd = p3[0];

    #pragma unroll 1
    for (int it = 0; it < 3; ++it) {
        float4 na, nb, nc, nd;
        bool nv = (it < 2) || (tid < 16);
        int noff = (it + 1) * 256;
        if (nv) { na = p0[noff]; nb = p1[noff]; nc = p2[noff]; nd = p3[noff]; }
        #pragma unroll
        for (int k = 0; k < 10; ++k) {
            float4 c = cb[(size_t)k * TD4 + it * 256];
            acc[0][k] += pa.x * c.x + pa.y * c.y + pa.z * c.z + pa.w * c.w;
            acc[1][k] += pb.x * c.x + pb.y * c.y + pb.z * c.z + pb.w * c.w;
            acc[2][k] += pc.x * c.x + pc.y * c.y + pc.z * c.z + pc.w * c.w;
            acc[3][k] += pd.x * c.x + pd.y * c.y + pd.z * c.z + pd.w * c.w;
        }
        if (nv) { pa = na; pb = nb; pc = nc; pd = nd; }
    }
    if (tid < 16) {
        #pragma unroll
        for (int k = 0; k < 10; ++k) {
            float4 c = cb[(size_t)k * TD4 + 768];
            acc[0][k] += pa.x * c.x + pa.y * c.y + pa.z * c.z + pa.w * c.w;
            acc[1][k] += pb.x * c.x + pb.y * c.y + pb.z * c.z + pb.w * c.w;
            acc[2][k] += pc.x * c.x + pc.y * c.y + pc.z * c.z + pc.w * c.w;
            acc[3][k] += pd.x * c.x + pd.y * c.y + pd.z * c.z + pd.w * c.w;
        }
    }

    #pragma unroll
    for (int j = 0; j < 4; ++j)
        #pragma unroll
        for (int k = 0; k < 10; ++k) {
            float v = acc[j][k];
            v += __shfl_xor(v, 1);
            v += __shfl_xor(v, 2);
            v += __shfl_xor(v, 4);
            v += __shfl_xor(v, 8);
            v += __shfl_xor(v, 16);
            v += __shfl_xor(v, 32);
            if (lane == j * 10 + k)
                part[((size_t)g * 32 + xb * 4 + wv) * 40 + j * 10 + k] = v;
        }
}

__global__ void k_reduce(const float* __restrict__ part,
                         const float* __restrict__ dpart,
                         const float* __restrict__ b_note, const float* __restrict__ b_reg,
                         float* __restrict__ out) {
    int idx = blockIdx.x * 256 + threadIdx.x;  // 0..5119
    int n = idx / 10, k = idx % 10;
    int g = n >> 2, j = n & 3;
    float s = (k < 2) ? b_note[k] : b_reg[k - 2];
    for (int b = 0; b < 8; ++b) s += dpart[k * 8 + b];
    for (int w = 0; w < 32; ++w) s += part[((size_t)g * 32 + w) * 40 + j * 10 + k];
    if (k < 2) out[n * 2 + k] = s;
    else       out[1024 + n * 8 + (k - 2)] = s;
}

extern "C" void kernel_launch(void* const* d_in, const int* in_sizes, int n_in,
                              void* d_out, int out_size, void* d_ws, size_t ws_size,
                              hipStream_t stream) {
    const float* proj   = (const float*)d_in[0];
    const float* w1     = (const float*)d_in[1];
    const float* b1     = (const float*)d_in[2];
    const float* w2     = (const float*)d_in[3];
    const float* b2     = (const float*)d_in[4];
    const float* w3     = (const float*)d_in[5];
    const float* b3     = (const float*)d_in[6];
    const float* w_note = (const float*)d_in[7];
    const float* b_note = (const float*)d_in[8];
    const float* w_reg  = (const float*)d_in[9];
    const float* b_reg  = (const float*)d_in[10];

    float* ws    = (float*)d_ws;
    float* WH    = ws;
    float* Y     = WH + 250880;
    float* T1    = Y + 262144;
    float* Bmat  = T1 + 250880;
    float* Tbuf  = Bmat + 250880;
    float* u2    = Tbuf + 12845056;
    float* vv    = u2 + 512;
    float* dpart = vv + 512;
    float* part  = dpart + 80;
    float* out   = (float*)d_out;

    k_whT<<<490, 512, 0, stream>>>(w_note, w_reg, WH);
    k_mmb<<<dim3(16, 16, 2), 256, 0, stream>>>(w1, w2, w3, WH, Y, T1);
    k_mm32<<<dim3(16, 16), 256, 0, stream>>>(T1, Y, Bmat, 490);
    k_mv1<<<512, 64, 0, stream>>>(w2, b1, b2, u2);
    k_mv2<<<512, 64, 0, stream>>>(w3, u2, b3, vv);
    k_dvec<<<dim3(10, 8), 256, 0, stream>>>(w_note, w_reg, vv, dpart);
    k_roi<<<8192, 256, 0, stream>>>(proj, Tbuf);
    k_fin<<<1024, 256, 0, stream>>>(Tbuf, Bmat, part);
    k_reduce<<<20, 256, 0, stream>>>(part, dpart, b_note, b_reg, out);
}

// Round 13
// 117.119 us; speedup vs baseline: 1.1251x; 1.1251x over previous
//
#include <hip/hip_runtime.h>

// out[n,k] = d[k] + sum_{ji,c} Bmat[k*49+ji][c] * bilinear_ji(proj[n,c,:,:])
// Bmat = WH·(w3·w2·w1)  (pipeline fully linear in project; boxes are constant).
//
// ONE fused pass over proj (k_mainf): block (n, ch=c/32) stages 25 KB
// contiguous -> LDS, computes 1568 bilinear values inline, dots against the
// ten Bmat slices (L2-resident, 1 MB total), butterfly-reduces, stores 40
// per-wave partials. No intermediate T buffer, no second big pass.
//
// ws layout (floats):
//   WH    [490][512]     off 0
//   Y     [512][512]     off 250880
//   T1    [490][512]     off 513024
//   Bmat  [490][512]     off 763904
//   u2    [512]          off 1014784
//   vv    [512]          off 1015296
//   dpart [10][8]        off 1015808
//   part  [8192*4][10]   off 1015888

#define CHW 100352   // 512*196
#define CHW4 25088   // float4 per proj row
#define STEP 1.8571428571428572f  // 13/7

// C[M x 512] = A[M x 512] * B[512 x 512]; 32x32 tile per block, thread = 2x2.
__global__ __launch_bounds__(256) void k_mm32(const float* __restrict__ A,
                                              const float* __restrict__ B,
                                              float* __restrict__ C, int M) {
    __shared__ float As[32][36];
    __shared__ float Bs[32][36];
    int bx = blockIdx.x, by = blockIdx.y;
    int tid = threadIdx.x;
    int lr = tid >> 3;
    int lc = (tid & 7) << 2;
    int tx = tid & 15, ty = tid >> 4;
    float a00 = 0.f, a01 = 0.f, a10 = 0.f, a11 = 0.f;
    for (int kc = 0; kc < 512; kc += 32) {
        int gr = by * 32 + lr;
        float4 av = make_float4(0.f, 0.f, 0.f, 0.f);
        if (gr < M) av = *(const float4*)&A[(size_t)gr * 512 + kc + lc];
        *(float4*)&As[lr][lc] = av;
        float4 bv = *(const float4*)&B[(size_t)(kc + lr) * 512 + bx * 32 + lc];
        *(float4*)&Bs[lr][lc] = bv;
        __syncthreads();
        #pragma unroll
        for (int kk = 0; kk < 32; ++kk) {
            float b0 = Bs[kk][tx * 2], b1 = Bs[kk][tx * 2 + 1];
            float x0 = As[ty * 2][kk], x1 = As[ty * 2 + 1][kk];
            a00 += x0 * b0; a01 += x0 * b1;
            a10 += x1 * b0; a11 += x1 * b1;
        }
        __syncthreads();
    }
    int r0 = by * 32 + ty * 2, c0 = bx * 32 + tx * 2;
    if (r0 < M)     { C[(size_t)r0 * 512 + c0] = a00; C[(size_t)r0 * 512 + c0 + 1] = a01; }
    if (r0 + 1 < M) { C[(size_t)(r0 + 1) * 512 + c0] = a10; C[(size_t)(r0 + 1) * 512 + c0 + 1] = a11; }
}

// Batched level-1: z=0 -> Y = w2*w1 (M=512); z=1 -> T1 = WH*w3 (M=490).
__global__ __launch_bounds__(256) void k_mmb(const float* __restrict__ w1,
                                             const float* __restrict__ w2,
                                             const float* __restrict__ w3,
                                             const float* __restrict__ WH,
                                             float* __restrict__ Y,
                                             float* __restrict__ T1) {
    __shared__ float As[32][36];
    __shared__ float Bs[32][36];
    const float* A; const float* B; float* C; int M;
    if (blockIdx.z == 0) { A = w2; B = w1; C = Y;  M = 512; }
    else                 { A = WH; B = w3; C = T1; M = 490; }
    int bx = blockIdx.x, by = blockIdx.y;
    int tid = threadIdx.x;
    int lr = tid >> 3;
    int lc = (tid & 7) << 2;
    int tx = tid & 15, ty = tid >> 4;
    float a00 = 0.f, a01 = 0.f, a10 = 0.f, a11 = 0.f;
    for (int kc = 0; kc < 512; kc += 32) {
        int gr = by * 32 + lr;
        float4 av = make_float4(0.f, 0.f, 0.f, 0.f);
        if (gr < M) av = *(const float4*)&A[(size_t)gr * 512 + kc + lc];
        *(float4*)&As[lr][lc] = av;
        float4 bv = *(const float4*)&B[(size_t)(kc + lr) * 512 + bx * 32 + lc];
        *(float4*)&Bs[lr][lc] = bv;
        __syncthreads();
        #pragma unroll
        for (int kk = 0; kk < 32; ++kk) {
            float b0 = Bs[kk][tx * 2], b1 = Bs[kk][tx * 2 + 1];
            float x0 = As[ty * 2][kk], x1 = As[ty * 2 + 1][kk];
            a00 += x0 * b0; a01 += x0 * b1;
            a10 += x1 * b0; a11 += x1 * b1;
        }
        __syncthreads();
    }
    int r0 = by * 32 + ty * 2, c0 = bx * 32 + tx * 2;
    if (r0 < M)     { C[(size_t)r0 * 512 + c0] = a00; C[(size_t)r0 * 512 + c0 + 1] = a01; }
    if (r0 + 1 < M) { C[(size_t)(r0 + 1) * 512 + c0] = a10; C[(size_t)(r0 + 1) * 512 + c0 + 1] = a11; }
}

// WH[r][q] = wh[k][q*49 + ji],  r = k*49 + ji
__global__ void k_whT(const float* __restrict__ w_note, const float* __restrict__ w_reg,
                      float* __restrict__ WH) {
    int r = blockIdx.x;      // 0..489
    int q = threadIdx.x;     // 0..511
    int k = r / 49, ji = r % 49;
    const float* wh = (k < 2) ? (w_note + k * 25088) : (w_reg + (k - 2) * 25088);
    WH[(size_t)r * 512 + q] = wh[q * 49 + ji];
}

// u2 = b2 + w2*b1
__global__ void k_mv1(const float* __restrict__ w2, const float* __restrict__ b1,
                      const float* __restrict__ b2, float* __restrict__ u2) {
    int o = blockIdx.x;
    int l = threadIdx.x;  // 64
    float s = 0.f;
    for (int i = l; i < 512; i += 64) s += w2[(size_t)o * 512 + i] * b1[i];
    for (int off = 32; off; off >>= 1) s += __shfl_down(s, off);
    if (l == 0) u2[o] = b2[o] + s;
}

// vv = b3 + w3*u2
__global__ void k_mv2(const float* __restrict__ w3, const float* __restrict__ u2,
                      const float* __restrict__ b3, float* __restrict__ vv) {
    int o = blockIdx.x;
    int l = threadIdx.x;  // 64
    float s = 0.f;
    for (int i = l; i < 512; i += 64) s += w3[(size_t)o * 512 + i] * u2[i];
    for (int off = 32; off; off >>= 1) s += __shfl_down(s, off);
    if (l == 0) vv[o] = b3[o] + s;
}

// dpart[k][b] = partial of sum_i wh[k][i] * vv[i/49]
__global__ void k_dvec(const float* __restrict__ w_note, const float* __restrict__ w_reg,
                       const float* __restrict__ vv, float* __restrict__ dpart) {
    int k = blockIdx.x;   // 10
    int b = blockIdx.y;   // 8
    int t = threadIdx.x;  // 256
    const float* wh = (k < 2) ? (w_note + k * 25088) : (w_reg + (k - 2) * 25088);
    float s = 0.f;
    for (int i = b * 256 + t; i < 25088; i += 2048) s += wh[i] * vv[i / 49];
    __shared__ float red[256];
    red[t] = s;
    __syncthreads();
    for (int off = 128; off; off >>= 1) {
        if (t < off) red[t] += red[t + off];
        __syncthreads();
    }
    if (t == 0) dpart[k * 8 + b] = red[0];
}

// Fused main: block b = n*16+ch. Stage 25 KB contiguous -> LDS; each thread
// computes ~7 bilinear samples and dots against the 10 Bmat slices (L2);
// butterfly reduce; per-wave partial store.
__global__ __launch_bounds__(256) void k_mainf(const float* __restrict__ proj,
                                               const float* __restrict__ Bmat,
                                               float* __restrict__ part) {
    __shared__ float X[32][197];   // 25,216 B; pad -> conflict-free
    int b = blockIdx.x;            // 0..8191
    int n = b >> 4;
    int ch = b & 15;               // c0 = ch*32
    int tid = threadIdx.x;
    int wv = tid >> 6, lane = tid & 63;

    const float4* src = (const float4*)proj + (size_t)n * CHW4 + ch * 1568;
    for (int i = tid; i < 1568; i += 256) {
        float4 v = src[i];
        int cc = i / 49, q = i - cc * 49;
        float* xr = &X[cc][q * 4];
        xr[0] = v.x; xr[1] = v.y; xr[2] = v.z; xr[3] = v.w;
    }
    __syncthreads();

    const float base = STEP * 0.5f - 0.5f;
    float acc[10];
    #pragma unroll
    for (int k = 0; k < 10; ++k) acc[k] = 0.f;

    for (int o = tid; o < 1568; o += 256) {
        int ji = o >> 5, cl = o & 31;
        int j = (ji * 37) >> 8;          // floor(ji/7) for ji<49
        int i2 = ji - j * 7;
        float yv = base + j * STEP;
        float xv = base + i2 * STEP;
        float y0f = floorf(yv), x0f = floorf(xv);
        float wy = yv - y0f, wx = xv - x0f;
        int i00 = (int)y0f * 14 + (int)x0f;
        const float* xr = X[cl];
        float v00 = xr[i00],      v01 = xr[i00 + 1];
        float v10 = xr[i00 + 14], v11 = xr[i00 + 15];
        float top = v00 + (v01 - v00) * wx;
        float bot = v10 + (v11 - v10) * wx;
        float v = top + (bot - top) * wy;
        int bidx = (ji << 9) + (ch << 5) + cl;
        #pragma unroll
        for (int k = 0; k < 10; ++k)
            acc[k] += v * Bmat[(size_t)k * 25088 + bidx];
    }

    #pragma unroll
    for (int k = 0; k < 10; ++k) {
        float v = acc[k];
        v += __shfl_xor(v, 1);
        v += __shfl_xor(v, 2);
        v += __shfl_xor(v, 4);
        v += __shfl_xor(v, 8);
        v += __shfl_xor(v, 16);
        v += __shfl_xor(v, 32);
        if (lane == k) part[((size_t)b * 4 + wv) * 10 + k] = v;
    }
}

// out[n,k] = dvec-sum + bias + sum over 64 wave-partials (16 ch x 4 wv)
__global__ void k_reduce(const float* __restrict__ part,
                         const float* __restrict__ dpart,
                         const float* __restrict__ b_note, const float* __restrict__ b_reg,
                         float* __restrict__ out) {
    int idx = blockIdx.x * 256 + threadIdx.x;  // 0..5119
    int n = idx / 10, k = idx % 10;
    float s = (k < 2) ? b_note[k] : b_reg[k - 2];
    for (int b = 0; b < 8; ++b) s += dpart[k * 8 + b];
    for (int w = 0; w < 64; ++w) s += part[((size_t)n * 64 + w) * 10 + k];
    if (k < 2) out[n * 2 + k] = s;
    else       out[1024 + n * 8 + (k - 2)] = s;
}

extern "C" void kernel_launch(void* const* d_in, const int* in_sizes, int n_in,
                              void* d_out, int out_size, void* d_ws, size_t ws_size,
                              hipStream_t stream) {
    const float* proj   = (const float*)d_in[0];
    const float* w1     = (const float*)d_in[1];
    const float* b1     = (const float*)d_in[2];
    const float* w2     = (const float*)d_in[3];
    const float* b2     = (const float*)d_in[4];
    const float* w3     = (const float*)d_in[5];
    const float* b3     = (const float*)d_in[6];
    const float* w_note = (const float*)d_in[7];
    const float* b_note = (const float*)d_in[8];
    const float* w_reg  = (const float*)d_in[9];
    const float* b_reg  = (const float*)d_in[10];

    float* ws    = (float*)d_ws;
    float* WH    = ws;
    float* Y     = WH + 250880;
    float* T1    = Y + 262144;
    float* Bmat  = T1 + 250880;
    float* u2    = Bmat + 250880;
    float* vv    = u2 + 512;
    float* dpart = vv + 512;
    float* part  = dpart + 80;
    float* out   = (float*)d_out;

    k_whT<<<490, 512, 0, stream>>>(w_note, w_reg, WH);
    k_mmb<<<dim3(16, 16, 2), 256, 0, stream>>>(w1, w2, w3, WH, Y, T1);
    k_mm32<<<dim3(16, 16), 256, 0, stream>>>(T1, Y, Bmat, 490);
    k_mv1<<<512, 64, 0, stream>>>(w2, b1, b2, u2);
    k_mv2<<<512, 64, 0, stream>>>(w3, u2, b3, vv);
    k_dvec<<<dim3(10, 8), 256, 0, stream>>>(w_note, w_reg, vv, dpart);
    k_mainf<<<8192, 256, 0, stream>>>(proj, Bmat, part);
    k_reduce<<<20, 256, 0, stream>>>(part, dpart, b_note, b_reg, out);
}